// Round 13
// baseline (471.495 us; speedup 1.0000x reference)
//
#include <hip/hip_runtime.h>
#include <hip/hip_bf16.h>

#define LEAKY 0.2f

typedef __attribute__((ext_vector_type(8))) short bf16x8;
typedef __attribute__((ext_vector_type(4))) float f32x4;
typedef __attribute__((ext_vector_type(2))) float f32x2;

// ---------------- CSR build (chunk-16 padded) ----------------

__global__ __launch_bounds__(256) void k_init(int* cnt, int* bstart, int n, int nb) {
    int i = blockIdx.x * 256 + threadIdx.x;
    if (i < n) cnt[i] = 1;            // self-loop pre-counted
    if (i < nb) bstart[i] = n;        // batch-boundary init
}

__global__ __launch_bounds__(256) void k_count(const int* __restrict__ dst, int* cnt, int e) {
    int i = blockIdx.x * 256 + threadIdx.x;
    if (i < e) atomicAdd(&cnt[dst[i]], 1);
}

// block-wide inclusive scan of one value per thread (256 threads)
__device__ inline int block_incl_scan(int v, int* lds) {
    int lane = threadIdx.x & 63, wid = threadIdx.x >> 6;
    int s = v;
#pragma unroll
    for (int o = 1; o < 64; o <<= 1) { int t = __shfl_up(s, o); if (lane >= o) s += t; }
    if (lane == 63) lds[wid] = s;
    __syncthreads();
    int add = 0;
#pragma unroll
    for (int ww = 0; ww < 3; ++ww) if (ww < wid) add += lds[ww];
    return s + add;
}

__global__ __launch_bounds__(256) void k_scanA(const int* __restrict__ cnt, int* bsum, int n) {
    __shared__ int lds[4];
    int i = blockIdx.x * 256 + threadIdx.x;
    int v = (i < n) ? ((cnt[i] + 15) & ~15) : 0;
    int s = block_incl_scan(v, lds);
    if (threadIdx.x == 255) bsum[blockIdx.x] = s;
}

__global__ __launch_bounds__(256) void k_scanB(int* bsum, int* boff, int nb) {
    __shared__ int lds[4];
    int i = threadIdx.x;
    int v = (i < nb) ? bsum[i] : 0;
    int s = block_incl_scan(v, lds);
    if (i < nb) boff[i] = s - v;   // exclusive
}

__global__ __launch_bounds__(256) void k_scanC(const int* __restrict__ cnt, const int* __restrict__ boff,
                                               int* row_ptr, int n) {
    __shared__ int lds[4];
    int i = blockIdx.x * 256 + threadIdx.x;
    int v = (i < n) ? ((cnt[i] + 15) & ~15) : 0;
    int s = block_incl_scan(v, lds) + boff[blockIdx.x];
    if (i < n) row_ptr[i + 1] = s;
    if (i == 0) row_ptr[0] = 0;
}

__global__ __launch_bounds__(256) void k_selfloop(const int* __restrict__ row_ptr, int* csr, int* cursor, int n) {
    int i = blockIdx.x * 256 + threadIdx.x;
    if (i < n) { int p = row_ptr[i]; csr[p] = i; cursor[i] = p + 1; }
}

__global__ __launch_bounds__(256) void k_scatter(const int* __restrict__ src, const int* __restrict__ dst,
                                                 int* cursor, int* csr, int e) {
    int i = blockIdx.x * 256 + threadIdx.x;
    if (i < e) { int p = atomicAdd(&cursor[dst[i]], 1); csr[p] = src[i]; }
}

// fill pad slots [cursor[i], row_ptr[i+1]) with own index + bit31 flag (zero weight)
__global__ __launch_bounds__(256) void k_pad(const int* __restrict__ row_ptr, const int* __restrict__ cursor,
                                             int* csr, int n) {
    int i = blockIdx.x * 256 + threadIdx.x;
    if (i >= n) return;
    int p = cursor[i], e = row_ptr[i + 1];
    int v = i | 0x80000000;
    for (; p < e; ++p) csr[p] = v;
}

__global__ __launch_bounds__(256) void k_bbounds(const int* __restrict__ bidx, int* bstart, int n) {
    int i = blockIdx.x * 256 + threadIdx.x;
    if (i < n) {
        int b = bidx[i];
        if (i == 0 || bidx[i - 1] != b) atomicMin(&bstart[b], i);
    }
}

__global__ void k_bfix(int* bstart, int n, int nb) {
    bstart[nb] = n;
    for (int b = nb - 1; b >= 0; --b)
        if (bstart[b] == n) bstart[b] = bstart[b + 1];
}

// round-nearest-even f32 -> bf16 (as ushort)
__device__ inline unsigned short bf16r(float x) {
    unsigned int u = __float_as_uint(x);
    u += 0x7fffu + ((u >> 16) & 1u);
    return (unsigned short)(u >> 16);
}

// round-nearest-even pack of two f32 into one uint (2×bf16, lo|hi<<16)
__device__ inline unsigned int bfpair(float lo, float hi) {
    unsigned int ul = __float_as_uint(lo); ul += 0x7fffu + ((ul >> 16) & 1u);
    unsigned int uh = __float_as_uint(hi); uh += 0x7fffu + ((uh >> 16) & 1u);
    return (ul >> 16) | (uh & 0xffff0000u);
}

// unpack u32 (2×bf16) -> float2
__device__ inline f32x2 unpk(unsigned int u) {
    f32x2 r;
    r.x = __uint_as_float(u << 16);
    r.y = __uint_as_float(u & 0xffff0000u);
    return r;
}

// ---------------- MFMA GEMM + attention logits (batched over all T snapshots) ----------------
// C[nrows x 128] = A[nrows x 128] @ W[128 x 128] in bf16 MFMA (f32 accumulate).
// Rows are t-major (row = t*N + n). Writes bf16-packed C (hb), vas/vad logits.
template <bool ABF16>
__global__ __launch_bounds__(256) void k_gemm_mfma(
    const void* __restrict__ Asrc, const float* __restrict__ W,
    const float* __restrict__ asrc, const float* __restrict__ adst,
    unsigned int* __restrict__ hb, float* __restrict__ vas, float* __restrict__ vad,
    int nrows)
{
    __shared__ unsigned short Wt[128 * 136];  // [n][k] bf16, padded
    __shared__ unsigned short At[128 * 40];   // [r][k0..k0+31] bf16, padded
    int tid = threadIdx.x;
    int lane = tid & 63, wv = tid >> 6;
    int row0 = blockIdx.x * 128;

    // ---- stage Wt = W^T (once) ----
    {
        int k = tid >> 1;
        int n0 = (tid & 1) * 64;
        const float4* wr = (const float4*)&W[k * 128 + n0];
#pragma unroll
        for (int i = 0; i < 16; ++i) {
            float4 v = wr[i];
            int n = n0 + i * 4;
            Wt[(n + 0) * 136 + k] = bf16r(v.x);
            Wt[(n + 1) * 136 + k] = bf16r(v.y);
            Wt[(n + 2) * 136 + k] = bf16r(v.z);
            Wt[(n + 3) * 136 + k] = bf16r(v.w);
        }
    }

    f32x4 acc[2][8];
#pragma unroll
    for (int mi = 0; mi < 2; ++mi)
#pragma unroll
        for (int ni = 0; ni < 8; ++ni)
#pragma unroll
            for (int q = 0; q < 4; ++q) acc[mi][ni][q] = 0.f;

    int r = tid >> 1, half = tid & 1;
    int rowA = min(row0 + r, nrows - 1);
    int c0 = lane & 15, g = lane >> 4;

    for (int ks = 0; ks < 4; ++ks) {
        int k0 = ks * 32;
        if (ks) __syncthreads();   // previous iteration's frag reads done
        // ---- stage At[r][k0..k0+31] ----
        if (ABF16) {
            const uint4* s4 = (const uint4*)((const unsigned int*)Asrc + (size_t)rowA * 64 + k0 / 2 + half * 8);
            uint4 v0 = s4[0], v1 = s4[1];
            *(uint4*)&At[r * 40 + half * 16]     = v0;
            *(uint4*)&At[r * 40 + half * 16 + 8] = v1;
        } else {
            const float4* s4 = (const float4*)((const float*)Asrc + (size_t)rowA * 128 + k0 + half * 16);
            float4 f0 = s4[0], f1 = s4[1], f2 = s4[2], f3 = s4[3];
            uint4 p0 = make_uint4(bfpair(f0.x, f0.y), bfpair(f0.z, f0.w), bfpair(f1.x, f1.y), bfpair(f1.z, f1.w));
            uint4 p1 = make_uint4(bfpair(f2.x, f2.y), bfpair(f2.z, f2.w), bfpair(f3.x, f3.y), bfpair(f3.z, f3.w));
            *(uint4*)&At[r * 40 + half * 16]     = p0;
            *(uint4*)&At[r * 40 + half * 16 + 8] = p1;
        }
        __syncthreads();

        bf16x8 af[2], bfr[8];
#pragma unroll
        for (int mi = 0; mi < 2; ++mi)
            af[mi] = *(const bf16x8*)&At[(wv * 32 + mi * 16 + c0) * 40 + g * 8];
#pragma unroll
        for (int ni = 0; ni < 8; ++ni)
            bfr[ni] = *(const bf16x8*)&Wt[(ni * 16 + c0) * 136 + k0 + g * 8];
#pragma unroll
        for (int mi = 0; mi < 2; ++mi)
#pragma unroll
            for (int ni = 0; ni < 8; ++ni)
                acc[mi][ni] = __builtin_amdgcn_mfma_f32_16x16x32_bf16(af[mi], bfr[ni], acc[mi][ni], 0, 0, 0);
    }

    // ---- epilogue: logits + bf16 pack ----
    float as_s[8], ad_s[8];
#pragma unroll
    for (int ni = 0; ni < 8; ++ni) {
        as_s[ni] = asrc[ni * 16 + c0];
        ad_s[ni] = adst[ni * 16 + c0];
    }
#pragma unroll
    for (int mi = 0; mi < 2; ++mi) {
#pragma unroll
        for (int reg = 0; reg < 4; ++reg) {
            int row = row0 + wv * 32 + mi * 16 + g * 4 + reg;
            bool rowok = row < nrows;
            float v[8];
            float s = 0.f, d = 0.f;
#pragma unroll
            for (int ni = 0; ni < 8; ++ni) {
                v[ni] = acc[mi][ni][reg];
                s = fmaf(v[ni], as_s[ni], s);
                d = fmaf(v[ni], ad_s[ni], d);
            }
#pragma unroll
            for (int o = 1; o < 16; o <<= 1) { s += __shfl_xor(s, o); d += __shfl_xor(d, o); }
            if (rowok && c0 == 0) { vas[row] = s; vad[row] = d; }
#pragma unroll
            for (int ni = 0; ni < 8; ++ni) {
                float vn = __shfl_xor(v[ni], 1);   // all lanes execute
                if (rowok && (c0 & 1) == 0)
                    hb[(size_t)row * 64 + ni * 8 + (c0 >> 1)] = bfpair(v[ni], vn);
            }
        }
    }
}

// ---------------- aggregation: 16-lane group per dst node, padded 16-edge chunks ----------------
// 1D grid with XCD t-affinity swizzle: block i -> t=(i&7)>>1, chunk=(i>>3)*2+(i&1).
// Consecutive blocks round-robin XCDs, so each XCD sees (mostly) one t-slice ->
// gather working set 12.8 MB instead of 51 MB. 32-bit gather offsets.
template <bool RELU>
__global__ __launch_bounds__(256, 8) void k_agg(const unsigned int* __restrict__ hb,
                                                const float* __restrict__ vas,
                                                const float* __restrict__ vad,
                                                const int* __restrict__ row_ptr,
                                                const int* __restrict__ csr,
                                                const float* __restrict__ bias,
                                                unsigned int* __restrict__ outb,
                                                int n, int chunksPerT) {
    int i = blockIdx.x;
    int t = (i & 7) >> 1;
    int chunk = ((i >> 3) << 1) | (i & 1);
    if (chunk >= chunksPerT) return;
    int tid = threadIdx.x;
    int grp = tid >> 4, l = tid & 15;
    int w = chunk * 16 + grp;
    if (w >= n) return;
    unsigned int tbase = (unsigned int)t * (unsigned int)n;  // snapshot offset in node-rows
    unsigned int g = tbase + (unsigned int)w;
    int beg = row_ptr[w], end = row_ptr[w + 1];
    float advl = vad[g];

    f32x2 acc2[4];
#pragma unroll
    for (int q = 0; q < 4; ++q) { acc2[q].x = 0.f; acc2[q].y = 0.f; }
    float zp = 0.f;

    for (int c = beg; c < end; c += 16) {
        int raw = csr[c + l];                       // coalesced
        unsigned int s_l = tbase + (unsigned int)(raw & 0x7fffffff);
        float e = vas[s_l] + advl;
        e = e > 0.f ? e : LEAKY * e;
        float w_l = (raw >= 0) ? __expf(e) : 0.f;   // pads contribute 0
        zp += w_l;

        unsigned int ofs[16]; float wt[16];
#pragma unroll
        for (int q = 0; q < 16; ++q) {
            ofs[q] = __shfl(s_l, q, 16) * 64u + (unsigned int)(l * 4);  // 32-bit offset
            wt[q] = __shfl(w_l, q, 16);
        }
        uint4 v[16];
#pragma unroll
        for (int q = 0; q < 16; ++q)
            v[q] = *(const uint4*)&hb[ofs[q]];
#pragma unroll
        for (int q = 0; q < 16; ++q) {
            f32x2 w2; w2.x = wt[q]; w2.y = wt[q];
            acc2[0] = __builtin_elementwise_fma(w2, unpk(v[q].x), acc2[0]);
            acc2[1] = __builtin_elementwise_fma(w2, unpk(v[q].y), acc2[1]);
            acc2[2] = __builtin_elementwise_fma(w2, unpk(v[q].z), acc2[2]);
            acc2[3] = __builtin_elementwise_fma(w2, unpk(v[q].w), acc2[3]);
        }
    }

    float z = zp;
#pragma unroll
    for (int o = 1; o < 16; o <<= 1) z += __shfl_xor(z, o, 16);
    float inv = 1.0f / z;

    float4 b0 = *(const float4*)&bias[l * 8];
    float4 b1 = *(const float4*)&bias[l * 8 + 4];
    float4 o0 = make_float4(fmaf(acc2[0].x, inv, b0.x), fmaf(acc2[0].y, inv, b0.y),
                            fmaf(acc2[1].x, inv, b0.z), fmaf(acc2[1].y, inv, b0.w));
    float4 o1 = make_float4(fmaf(acc2[2].x, inv, b1.x), fmaf(acc2[2].y, inv, b1.y),
                            fmaf(acc2[3].x, inv, b1.z), fmaf(acc2[3].y, inv, b1.w));
    if (RELU) {
        o0.x = fmaxf(o0.x, 0.f); o0.y = fmaxf(o0.y, 0.f); o0.z = fmaxf(o0.z, 0.f); o0.w = fmaxf(o0.w, 0.f);
        o1.x = fmaxf(o1.x, 0.f); o1.y = fmaxf(o1.y, 0.f); o1.z = fmaxf(o1.z, 0.f); o1.w = fmaxf(o1.w, 0.f);
    }
    uint4 p = make_uint4(bfpair(o0.x, o0.y), bfpair(o0.z, o0.w),
                         bfpair(o1.x, o1.y), bfpair(o1.z, o1.w));
    *(uint4*)&outb[(size_t)g * 64 + l * 4] = p;
}

// ---------------- batch mean pool (batch_idx sorted), bf16 t-major input ----------------
__global__ __launch_bounds__(128) void k_pool(const unsigned int* __restrict__ h,
                                              const int* __restrict__ bstart,
                                              float* __restrict__ out, int n, int T) {
    int b = blockIdx.x;
    int chunk = blockIdx.y;
    int t = blockIdx.z;
    int f = threadIdx.x;
    int s = bstart[b], e = bstart[b + 1];
    int cnt = e - s;
    if (cnt <= 0) return;
    int len = (cnt + 31) / 32;
    int cs = s + chunk * len;
    int ce = min(cs + len, e);
    if (cs >= ce) return;
    const unsigned int* ht = h + (size_t)t * n * 64;
    float acc = 0.f;
    for (int nidx = cs; nidx < ce; ++nidx) {
        unsigned int v = ht[(size_t)nidx * 64 + (f >> 1)];
        acc += __uint_as_float((f & 1) ? (v & 0xffff0000u) : (v << 16));
    }
    atomicAdd(&out[(size_t)(b * T + t) * 128 + f], acc / (float)cnt);
}

// ---------------- launch ----------------

extern "C" void kernel_launch(void* const* d_in, const int* in_sizes, int n_in,
                              void* d_out, int out_size, void* d_ws, size_t ws_size,
                              hipStream_t stream) {
    const float* x    = (const float*)d_in[0];
    const int*   ei   = (const int*)d_in[1];
    const int*   bidx = (const int*)d_in[2];
    const float* W1   = (const float*)d_in[3];
    const float* as1  = (const float*)d_in[4];
    const float* ad1  = (const float*)d_in[5];
    const float* b1   = (const float*)d_in[6];
    const float* W2   = (const float*)d_in[7];
    const float* as2  = (const float*)d_in[8];
    const float* ad2  = (const float*)d_in[9];
    const float* b2   = (const float*)d_in[10];
    float* out = (float*)d_out;

    const int E = in_sizes[1] / 2;
    const int N = in_sizes[2];
    const int T = in_sizes[0] / (N * 128);   // == 4 for this problem (swizzle assumes 4)
    const int B = out_size / (T * 128);
    const int* src = ei;
    const int* dst = ei + E;
    const int NT = N * T;

    char* wsp = (char*)d_ws;
    auto alloc = [&](size_t bytes) { void* p = wsp; wsp += (bytes + 255) / 256 * 256; return p; };
    unsigned int* hb     = (unsigned int*)alloc((size_t)NT * 64 * 4);  // bf16 GEMM out, t-major
    unsigned int* hb2    = (unsigned int*)alloc((size_t)NT * 64 * 4);  // bf16 agg out, t-major
    float* vas           = (float*)alloc((size_t)NT * 4);
    float* vad           = (float*)alloc((size_t)NT * 4);
    int* row_ptr         = (int*)alloc((size_t)(N + 1) * 4);
    int* cnt             = (int*)alloc((size_t)N * 4);                 // reused as scatter cursor
    int* csr             = (int*)alloc(((size_t)E + 16ull * N + 64) * 4); // padded CSR
    int* bstart          = (int*)alloc((size_t)(B + 2) * 4);
    int  nScanB          = (N + 255) / 256;
    int* bsum            = (int*)alloc((size_t)nScanB * 4);
    int* boff            = (int*)alloc((size_t)nScanB * 4);

    hipMemsetAsync(d_out, 0, (size_t)out_size * sizeof(float), stream);

    int gN = (N + 255) / 256, gE = (E + 255) / 256;
    k_init<<<gN, 256, 0, stream>>>(cnt, bstart, N, B + 1);
    k_count<<<gE, 256, 0, stream>>>(dst, cnt, E);
    k_scanA<<<nScanB, 256, 0, stream>>>(cnt, bsum, N);
    k_scanB<<<1, 256, 0, stream>>>(bsum, boff, nScanB);
    k_scanC<<<nScanB, 256, 0, stream>>>(cnt, boff, row_ptr, N);
    k_selfloop<<<gN, 256, 0, stream>>>(row_ptr, csr, cnt, N);
    k_scatter<<<gE, 256, 0, stream>>>(src, dst, cnt, csr, E);
    k_pad<<<gN, 256, 0, stream>>>(row_ptr, cnt, csr, N);
    k_bbounds<<<gN, 256, 0, stream>>>(bidx, bstart, N);
    k_bfix<<<1, 1, 0, stream>>>(bstart, N, B);

    int gGemm = (NT + 127) / 128;
    int chunksPerT = (N + 15) / 16;                 // 16 nodes per block per t
    int chunksPad = ((chunksPerT + 1) / 2) * 2;     // even, for the i&1 swizzle bit
    int gAggFlat = chunksPad * 4;                   // T==4 snapshots
    k_gemm_mfma<false><<<gGemm, 256, 0, stream>>>(x,   W1, as1, ad1, hb, vas, vad, NT);
    k_agg<true ><<<gAggFlat, 256, 0, stream>>>(hb, vas, vad, row_ptr, csr, b1, hb2, N, chunksPerT);
    k_gemm_mfma<true ><<<gGemm, 256, 0, stream>>>(hb2, W2, as2, ad2, hb, vas, vad, NT);
    k_agg<false><<<gAggFlat, 256, 0, stream>>>(hb, vas, vad, row_ptr, csr, b2, hb2, N, chunksPerT);
    k_pool<<<dim3(B, 32, T), 128, 0, stream>>>(hb2, bstart, out, N, T);
}

// Round 14
// 351.599 us; speedup vs baseline: 1.3410x; 1.3410x over previous
//
#include <hip/hip_runtime.h>
#include <hip/hip_bf16.h>

#define LEAKY 0.2f

typedef __attribute__((ext_vector_type(8))) short bf16x8;
typedef __attribute__((ext_vector_type(4))) float f32x4;
typedef __attribute__((ext_vector_type(2))) float f32x2;

// ---------------- CSR build (chunk-16 padded) ----------------

__global__ __launch_bounds__(256) void k_init(int* cnt, int* bstart, int n, int nb) {
    int i = blockIdx.x * 256 + threadIdx.x;
    if (i < n) cnt[i] = 1;            // self-loop pre-counted
    if (i < nb) bstart[i] = n;        // batch-boundary init
}

__global__ __launch_bounds__(256) void k_count(const int* __restrict__ dst, int* cnt, int e) {
    int i = blockIdx.x * 256 + threadIdx.x;
    if (i < e) atomicAdd(&cnt[dst[i]], 1);
}

// block-wide inclusive scan of one value per thread (256 threads)
__device__ inline int block_incl_scan(int v, int* lds) {
    int lane = threadIdx.x & 63, wid = threadIdx.x >> 6;
    int s = v;
#pragma unroll
    for (int o = 1; o < 64; o <<= 1) { int t = __shfl_up(s, o); if (lane >= o) s += t; }
    if (lane == 63) lds[wid] = s;
    __syncthreads();
    int add = 0;
#pragma unroll
    for (int ww = 0; ww < 3; ++ww) if (ww < wid) add += lds[ww];
    return s + add;
}

__global__ __launch_bounds__(256) void k_scanA(const int* __restrict__ cnt, int* bsum, int n) {
    __shared__ int lds[4];
    int i = blockIdx.x * 256 + threadIdx.x;
    int v = (i < n) ? ((cnt[i] + 15) & ~15) : 0;
    int s = block_incl_scan(v, lds);
    if (threadIdx.x == 255) bsum[blockIdx.x] = s;
}

__global__ __launch_bounds__(256) void k_scanB(int* bsum, int* boff, int nb) {
    __shared__ int lds[4];
    int i = threadIdx.x;
    int v = (i < nb) ? bsum[i] : 0;
    int s = block_incl_scan(v, lds);
    if (i < nb) boff[i] = s - v;   // exclusive
}

__global__ __launch_bounds__(256) void k_scanC(const int* __restrict__ cnt, const int* __restrict__ boff,
                                               int* row_ptr, int n) {
    __shared__ int lds[4];
    int i = blockIdx.x * 256 + threadIdx.x;
    int v = (i < n) ? ((cnt[i] + 15) & ~15) : 0;
    int s = block_incl_scan(v, lds) + boff[blockIdx.x];
    if (i < n) row_ptr[i + 1] = s;
    if (i == 0) row_ptr[0] = 0;
}

__global__ __launch_bounds__(256) void k_selfloop(const int* __restrict__ row_ptr, int* csr, int* cursor, int n) {
    int i = blockIdx.x * 256 + threadIdx.x;
    if (i < n) { int p = row_ptr[i]; csr[p] = i; cursor[i] = p + 1; }
}

__global__ __launch_bounds__(256) void k_scatter(const int* __restrict__ src, const int* __restrict__ dst,
                                                 int* cursor, int* csr, int e) {
    int i = blockIdx.x * 256 + threadIdx.x;
    if (i < e) { int p = atomicAdd(&cursor[dst[i]], 1); csr[p] = src[i]; }
}

// fill pad slots [cursor[i], row_ptr[i+1]) with own index + bit31 flag (zero weight)
__global__ __launch_bounds__(256) void k_pad(const int* __restrict__ row_ptr, const int* __restrict__ cursor,
                                             int* csr, int n) {
    int i = blockIdx.x * 256 + threadIdx.x;
    if (i >= n) return;
    int p = cursor[i], e = row_ptr[i + 1];
    int v = i | 0x80000000;
    for (; p < e; ++p) csr[p] = v;
}

__global__ __launch_bounds__(256) void k_bbounds(const int* __restrict__ bidx, int* bstart, int n) {
    int i = blockIdx.x * 256 + threadIdx.x;
    if (i < n) {
        int b = bidx[i];
        if (i == 0 || bidx[i - 1] != b) atomicMin(&bstart[b], i);
    }
}

__global__ void k_bfix(int* bstart, int n, int nb) {
    bstart[nb] = n;
    for (int b = nb - 1; b >= 0; --b)
        if (bstart[b] == n) bstart[b] = bstart[b + 1];
}

// round-nearest-even f32 -> bf16 (as ushort)
__device__ inline unsigned short bf16r(float x) {
    unsigned int u = __float_as_uint(x);
    u += 0x7fffu + ((u >> 16) & 1u);
    return (unsigned short)(u >> 16);
}

// round-nearest-even pack of two f32 into one uint (2×bf16, lo|hi<<16)
__device__ inline unsigned int bfpair(float lo, float hi) {
    unsigned int ul = __float_as_uint(lo); ul += 0x7fffu + ((ul >> 16) & 1u);
    unsigned int uh = __float_as_uint(hi); uh += 0x7fffu + ((uh >> 16) & 1u);
    return (ul >> 16) | (uh & 0xffff0000u);
}

// ---------------- MFMA GEMM + attention logits (batched over all T snapshots) ----------------
// C[nrows x 128] = A[nrows x 128] @ W[128 x 128] in bf16 MFMA (f32 accumulate).
// Rows t-major (row = t*N + n). Writes FP8 e4m3 C rows (hq, 128 B/row) for the gather,
// plus f32 logits vas/vad. A-input: f32 (layer1) or bf16-packed (layer2).
template <bool ABF16>
__global__ __launch_bounds__(256) void k_gemm_mfma(
    const void* __restrict__ Asrc, const float* __restrict__ W,
    const float* __restrict__ asrc, const float* __restrict__ adst,
    unsigned char* __restrict__ hq, float* __restrict__ vas, float* __restrict__ vad,
    int nrows)
{
    __shared__ unsigned short Wt[128 * 136];  // [n][k] bf16, padded
    __shared__ unsigned short At[128 * 40];   // [r][k0..k0+31] bf16, padded
    int tid = threadIdx.x;
    int lane = tid & 63, wv = tid >> 6;
    int row0 = blockIdx.x * 128;

    // ---- stage Wt = W^T (once) ----
    {
        int k = tid >> 1;
        int n0 = (tid & 1) * 64;
        const float4* wr = (const float4*)&W[k * 128 + n0];
#pragma unroll
        for (int i = 0; i < 16; ++i) {
            float4 v = wr[i];
            int n = n0 + i * 4;
            Wt[(n + 0) * 136 + k] = bf16r(v.x);
            Wt[(n + 1) * 136 + k] = bf16r(v.y);
            Wt[(n + 2) * 136 + k] = bf16r(v.z);
            Wt[(n + 3) * 136 + k] = bf16r(v.w);
        }
    }

    f32x4 acc[2][8];
#pragma unroll
    for (int mi = 0; mi < 2; ++mi)
#pragma unroll
        for (int ni = 0; ni < 8; ++ni)
#pragma unroll
            for (int q = 0; q < 4; ++q) acc[mi][ni][q] = 0.f;

    int r = tid >> 1, half = tid & 1;
    int rowA = min(row0 + r, nrows - 1);
    int c0 = lane & 15, g = lane >> 4;

    for (int ks = 0; ks < 4; ++ks) {
        int k0 = ks * 32;
        if (ks) __syncthreads();   // previous iteration's frag reads done
        // ---- stage At[r][k0..k0+31] ----
        if (ABF16) {
            const uint4* s4 = (const uint4*)((const unsigned int*)Asrc + (size_t)rowA * 64 + k0 / 2 + half * 8);
            uint4 v0 = s4[0], v1 = s4[1];
            *(uint4*)&At[r * 40 + half * 16]     = v0;
            *(uint4*)&At[r * 40 + half * 16 + 8] = v1;
        } else {
            const float4* s4 = (const float4*)((const float*)Asrc + (size_t)rowA * 128 + k0 + half * 16);
            float4 f0 = s4[0], f1 = s4[1], f2 = s4[2], f3 = s4[3];
            uint4 p0 = make_uint4(bfpair(f0.x, f0.y), bfpair(f0.z, f0.w), bfpair(f1.x, f1.y), bfpair(f1.z, f1.w));
            uint4 p1 = make_uint4(bfpair(f2.x, f2.y), bfpair(f2.z, f2.w), bfpair(f3.x, f3.y), bfpair(f3.z, f3.w));
            *(uint4*)&At[r * 40 + half * 16]     = p0;
            *(uint4*)&At[r * 40 + half * 16 + 8] = p1;
        }
        __syncthreads();

        bf16x8 af[2], bfr[8];
#pragma unroll
        for (int mi = 0; mi < 2; ++mi)
            af[mi] = *(const bf16x8*)&At[(wv * 32 + mi * 16 + c0) * 40 + g * 8];
#pragma unroll
        for (int ni = 0; ni < 8; ++ni)
            bfr[ni] = *(const bf16x8*)&Wt[(ni * 16 + c0) * 136 + k0 + g * 8];
#pragma unroll
        for (int mi = 0; mi < 2; ++mi)
#pragma unroll
            for (int ni = 0; ni < 8; ++ni)
                acc[mi][ni] = __builtin_amdgcn_mfma_f32_16x16x32_bf16(af[mi], bfr[ni], acc[mi][ni], 0, 0, 0);
    }

    // ---- epilogue: logits (f32) + fp8 pack ----
    float as_s[8], ad_s[8];
#pragma unroll
    for (int ni = 0; ni < 8; ++ni) {
        as_s[ni] = asrc[ni * 16 + c0];
        ad_s[ni] = adst[ni * 16 + c0];
    }
#pragma unroll
    for (int mi = 0; mi < 2; ++mi) {
#pragma unroll
        for (int reg = 0; reg < 4; ++reg) {
            int row = row0 + wv * 32 + mi * 16 + g * 4 + reg;
            bool rowok = row < nrows;
            float v[8];
            float s = 0.f, d = 0.f;
#pragma unroll
            for (int ni = 0; ni < 8; ++ni) {
                v[ni] = acc[mi][ni][reg];
                s = fmaf(v[ni], as_s[ni], s);
                d = fmaf(v[ni], ad_s[ni], d);
            }
#pragma unroll
            for (int o = 1; o < 16; o <<= 1) { s += __shfl_xor(s, o); d += __shfl_xor(d, o); }
            if (rowok && c0 == 0) { vas[row] = s; vad[row] = d; }
#pragma unroll
            for (int ni = 0; ni < 8; ++ni) {
                float vn = __shfl_xor(v[ni], 1);   // all lanes execute
                unsigned int w = (unsigned int)__builtin_amdgcn_cvt_pk_fp8_f32(v[ni], vn, 0, false);
                if (rowok && (c0 & 1) == 0)
                    *(unsigned short*)&hq[(size_t)row * 128 + ni * 16 + c0] = (unsigned short)w;
            }
        }
    }
}

// ---------------- aggregation: 16-lane group per dst node, padded 16-edge chunks ----------------
// grid (gAgg, T), t-major tables. FP8 gather: 8 B/lane (8 fp8 feats), native cvt_pk unpack.
// Output bf16-packed rows (agg1 -> GEMM2 input; agg2 -> pool input).
template <bool RELU>
__global__ __launch_bounds__(256) void k_agg(const unsigned char* __restrict__ hq,
                                             const float* __restrict__ vas,
                                             const float* __restrict__ vad,
                                             const int* __restrict__ row_ptr,
                                             const int* __restrict__ csr,
                                             const float* __restrict__ bias,
                                             unsigned int* __restrict__ outb, int n) {
    int tid = threadIdx.x;
    int grp = tid >> 4, l = tid & 15;
    int w = blockIdx.x * 16 + grp;
    if (w >= n) return;
    unsigned int tbase = (unsigned int)blockIdx.y * (unsigned int)n;
    unsigned int g = tbase + (unsigned int)w;
    int beg = row_ptr[w], end = row_ptr[w + 1];
    float advl = vad[g];

    f32x2 acc2[4];
#pragma unroll
    for (int q = 0; q < 4; ++q) { acc2[q].x = 0.f; acc2[q].y = 0.f; }
    float zp = 0.f;

    for (int c = beg; c < end; c += 16) {
        int raw = csr[c + l];                       // coalesced
        unsigned int s_l = tbase + (unsigned int)(raw & 0x7fffffff);
        float e = vas[s_l] + advl;
        e = e > 0.f ? e : LEAKY * e;
        float w_l = (raw >= 0) ? __expf(e) : 0.f;   // pads contribute 0
        zp += w_l;

        unsigned int ofs[16]; float wt[16];
#pragma unroll
        for (int q = 0; q < 16; ++q) {
            ofs[q] = __shfl(s_l, q, 16) * 128u + (unsigned int)(l * 8);  // 32-bit byte offset
            wt[q] = __shfl(w_l, q, 16);
        }
        uint2 v[16];
#pragma unroll
        for (int q = 0; q < 16; ++q)
            v[q] = *(const uint2*)&hq[ofs[q]];
#pragma unroll
        for (int q = 0; q < 16; ++q) {
            f32x2 w2; w2.x = wt[q]; w2.y = wt[q];
            acc2[0] = __builtin_elementwise_fma(w2, __builtin_amdgcn_cvt_pk_f32_fp8(v[q].x, false), acc2[0]);
            acc2[1] = __builtin_elementwise_fma(w2, __builtin_amdgcn_cvt_pk_f32_fp8(v[q].x, true),  acc2[1]);
            acc2[2] = __builtin_elementwise_fma(w2, __builtin_amdgcn_cvt_pk_f32_fp8(v[q].y, false), acc2[2]);
            acc2[3] = __builtin_elementwise_fma(w2, __builtin_amdgcn_cvt_pk_f32_fp8(v[q].y, true),  acc2[3]);
        }
    }

    float z = zp;
#pragma unroll
    for (int o = 1; o < 16; o <<= 1) z += __shfl_xor(z, o, 16);
    float inv = 1.0f / z;

    float4 b0 = *(const float4*)&bias[l * 8];
    float4 b1 = *(const float4*)&bias[l * 8 + 4];
    float4 o0 = make_float4(fmaf(acc2[0].x, inv, b0.x), fmaf(acc2[0].y, inv, b0.y),
                            fmaf(acc2[1].x, inv, b0.z), fmaf(acc2[1].y, inv, b0.w));
    float4 o1 = make_float4(fmaf(acc2[2].x, inv, b1.x), fmaf(acc2[2].y, inv, b1.y),
                            fmaf(acc2[3].x, inv, b1.z), fmaf(acc2[3].y, inv, b1.w));
    if (RELU) {
        o0.x = fmaxf(o0.x, 0.f); o0.y = fmaxf(o0.y, 0.f); o0.z = fmaxf(o0.z, 0.f); o0.w = fmaxf(o0.w, 0.f);
        o1.x = fmaxf(o1.x, 0.f); o1.y = fmaxf(o1.y, 0.f); o1.z = fmaxf(o1.z, 0.f); o1.w = fmaxf(o1.w, 0.f);
    }
    uint4 p = make_uint4(bfpair(o0.x, o0.y), bfpair(o0.z, o0.w),
                         bfpair(o1.x, o1.y), bfpair(o1.z, o1.w));
    *(uint4*)&outb[(size_t)g * 64 + l * 4] = p;
}

// ---------------- batch mean pool (batch_idx sorted), bf16 t-major input ----------------
__global__ __launch_bounds__(128) void k_pool(const unsigned int* __restrict__ h,
                                              const int* __restrict__ bstart,
                                              float* __restrict__ out, int n, int T) {
    int b = blockIdx.x;
    int chunk = blockIdx.y;
    int t = blockIdx.z;
    int f = threadIdx.x;
    int s = bstart[b], e = bstart[b + 1];
    int cnt = e - s;
    if (cnt <= 0) return;
    int len = (cnt + 31) / 32;
    int cs = s + chunk * len;
    int ce = min(cs + len, e);
    if (cs >= ce) return;
    const unsigned int* ht = h + (size_t)t * n * 64;
    float acc = 0.f;
    for (int nidx = cs; nidx < ce; ++nidx) {
        unsigned int v = ht[(size_t)nidx * 64 + (f >> 1)];
        acc += __uint_as_float((f & 1) ? (v & 0xffff0000u) : (v << 16));
    }
    atomicAdd(&out[(size_t)(b * T + t) * 128 + f], acc / (float)cnt);
}

// ---------------- launch ----------------

extern "C" void kernel_launch(void* const* d_in, const int* in_sizes, int n_in,
                              void* d_out, int out_size, void* d_ws, size_t ws_size,
                              hipStream_t stream) {
    const float* x    = (const float*)d_in[0];
    const int*   ei   = (const int*)d_in[1];
    const int*   bidx = (const int*)d_in[2];
    const float* W1   = (const float*)d_in[3];
    const float* as1  = (const float*)d_in[4];
    const float* ad1  = (const float*)d_in[5];
    const float* b1   = (const float*)d_in[6];
    const float* W2   = (const float*)d_in[7];
    const float* as2  = (const float*)d_in[8];
    const float* ad2  = (const float*)d_in[9];
    const float* b2   = (const float*)d_in[10];
    float* out = (float*)d_out;

    const int E = in_sizes[1] / 2;
    const int N = in_sizes[2];
    const int T = in_sizes[0] / (N * 128);
    const int B = out_size / (T * 128);
    const int* src = ei;
    const int* dst = ei + E;
    const int NT = N * T;

    char* wsp = (char*)d_ws;
    auto alloc = [&](size_t bytes) { void* p = wsp; wsp += (bytes + 255) / 256 * 256; return p; };
    unsigned char* hq    = (unsigned char*)alloc((size_t)NT * 128);    // fp8 GEMM out (gather table)
    unsigned int* hb2    = (unsigned int*)alloc((size_t)NT * 64 * 4);  // bf16 agg out, t-major
    float* vas           = (float*)alloc((size_t)NT * 4);
    float* vad           = (float*)alloc((size_t)NT * 4);
    int* row_ptr         = (int*)alloc((size_t)(N + 1) * 4);
    int* cnt             = (int*)alloc((size_t)N * 4);                 // reused as scatter cursor
    int* csr             = (int*)alloc(((size_t)E + 16ull * N + 64) * 4); // padded CSR
    int* bstart          = (int*)alloc((size_t)(B + 2) * 4);
    int  nScanB          = (N + 255) / 256;
    int* bsum            = (int*)alloc((size_t)nScanB * 4);
    int* boff            = (int*)alloc((size_t)nScanB * 4);

    hipMemsetAsync(d_out, 0, (size_t)out_size * sizeof(float), stream);

    int gN = (N + 255) / 256, gE = (E + 255) / 256;
    k_init<<<gN, 256, 0, stream>>>(cnt, bstart, N, B + 1);
    k_count<<<gE, 256, 0, stream>>>(dst, cnt, E);
    k_scanA<<<nScanB, 256, 0, stream>>>(cnt, bsum, N);
    k_scanB<<<1, 256, 0, stream>>>(bsum, boff, nScanB);
    k_scanC<<<nScanB, 256, 0, stream>>>(cnt, boff, row_ptr, N);
    k_selfloop<<<gN, 256, 0, stream>>>(row_ptr, csr, cnt, N);
    k_scatter<<<gE, 256, 0, stream>>>(src, dst, cnt, csr, E);
    k_pad<<<gN, 256, 0, stream>>>(row_ptr, cnt, csr, N);
    k_bbounds<<<gN, 256, 0, stream>>>(bidx, bstart, N);
    k_bfix<<<1, 1, 0, stream>>>(bstart, N, B);

    int gGemm = (NT + 127) / 128;
    int gAgg = (N + 15) / 16;  // 16 nodes (16-lane groups) per 256-thread block
    k_gemm_mfma<false><<<gGemm, 256, 0, stream>>>(x,   W1, as1, ad1, hq, vas, vad, NT);
    k_agg<true ><<<dim3(gAgg, T), 256, 0, stream>>>(hq, vas, vad, row_ptr, csr, b1, hb2, N);
    k_gemm_mfma<true ><<<gGemm, 256, 0, stream>>>(hb2, W2, as2, ad2, hq, vas, vad, NT);
    k_agg<false><<<dim3(gAgg, T), 256, 0, stream>>>(hq, vas, vad, row_ptr, csr, b2, hb2, N);
    k_pool<<<dim3(B, 32, T), 128, 0, stream>>>(hb2, bstart, out, N, T);
}

// Round 15
// 345.846 us; speedup vs baseline: 1.3633x; 1.0166x over previous
//
#include <hip/hip_runtime.h>
#include <hip/hip_bf16.h>

#define LEAKY 0.2f

typedef __attribute__((ext_vector_type(8))) short bf16x8;
typedef __attribute__((ext_vector_type(4))) float f32x4;
typedef __attribute__((ext_vector_type(2))) float f32x2;

// ---------------- CSR build (chunk-16 padded) ----------------

__global__ __launch_bounds__(256) void k_init(int* cnt, int* bstart, int n, int nb) {
    int i = blockIdx.x * 256 + threadIdx.x;
    if (i < n) cnt[i] = 1;            // self-loop pre-counted
    if (i < nb) bstart[i] = n;        // batch-boundary init
}

__global__ __launch_bounds__(256) void k_count(const int* __restrict__ dst, int* cnt, int e) {
    int i = blockIdx.x * 256 + threadIdx.x;
    if (i < e) atomicAdd(&cnt[dst[i]], 1);
}

// block-wide inclusive scan of one value per thread (256 threads)
__device__ inline int block_incl_scan(int v, int* lds) {
    int lane = threadIdx.x & 63, wid = threadIdx.x >> 6;
    int s = v;
#pragma unroll
    for (int o = 1; o < 64; o <<= 1) { int t = __shfl_up(s, o); if (lane >= o) s += t; }
    if (lane == 63) lds[wid] = s;
    __syncthreads();
    int add = 0;
#pragma unroll
    for (int ww = 0; ww < 3; ++ww) if (ww < wid) add += lds[ww];
    return s + add;
}

__global__ __launch_bounds__(256) void k_scanA(const int* __restrict__ cnt, int* bsum, int n) {
    __shared__ int lds[4];
    int i = blockIdx.x * 256 + threadIdx.x;
    int v = (i < n) ? ((cnt[i] + 15) & ~15) : 0;
    int s = block_incl_scan(v, lds);
    if (threadIdx.x == 255) bsum[blockIdx.x] = s;
}

__global__ __launch_bounds__(256) void k_scanB(int* bsum, int* boff, int nb) {
    __shared__ int lds[4];
    int i = threadIdx.x;
    int v = (i < nb) ? bsum[i] : 0;
    int s = block_incl_scan(v, lds);
    if (i < nb) boff[i] = s - v;   // exclusive
}

__global__ __launch_bounds__(256) void k_scanC(const int* __restrict__ cnt, const int* __restrict__ boff,
                                               int* row_ptr, int n) {
    __shared__ int lds[4];
    int i = blockIdx.x * 256 + threadIdx.x;
    int v = (i < n) ? ((cnt[i] + 15) & ~15) : 0;
    int s = block_incl_scan(v, lds) + boff[blockIdx.x];
    if (i < n) row_ptr[i + 1] = s;
    if (i == 0) row_ptr[0] = 0;
}

__global__ __launch_bounds__(256) void k_selfloop(const int* __restrict__ row_ptr, int* csr, int* cursor, int n) {
    int i = blockIdx.x * 256 + threadIdx.x;
    if (i < n) { int p = row_ptr[i]; csr[p] = i; cursor[i] = p + 1; }
}

__global__ __launch_bounds__(256) void k_scatter(const int* __restrict__ src, const int* __restrict__ dst,
                                                 int* cursor, int* csr, int e) {
    int i = blockIdx.x * 256 + threadIdx.x;
    if (i < e) { int p = atomicAdd(&cursor[dst[i]], 1); csr[p] = src[i]; }
}

// fill pad slots [cursor[i], row_ptr[i+1]) with own index + bit31 flag (zero weight)
__global__ __launch_bounds__(256) void k_pad(const int* __restrict__ row_ptr, const int* __restrict__ cursor,
                                             int* csr, int n) {
    int i = blockIdx.x * 256 + threadIdx.x;
    if (i >= n) return;
    int p = cursor[i], e = row_ptr[i + 1];
    int v = i | 0x80000000;
    for (; p < e; ++p) csr[p] = v;
}

__global__ __launch_bounds__(256) void k_bbounds(const int* __restrict__ bidx, int* bstart, int n) {
    int i = blockIdx.x * 256 + threadIdx.x;
    if (i < n) {
        int b = bidx[i];
        if (i == 0 || bidx[i - 1] != b) atomicMin(&bstart[b], i);
    }
}

__global__ void k_bfix(int* bstart, int n, int nb) {
    bstart[nb] = n;
    for (int b = nb - 1; b >= 0; --b)
        if (bstart[b] == n) bstart[b] = bstart[b + 1];
}

// round-nearest-even f32 -> bf16 (as ushort)
__device__ inline unsigned short bf16r(float x) {
    unsigned int u = __float_as_uint(x);
    u += 0x7fffu + ((u >> 16) & 1u);
    return (unsigned short)(u >> 16);
}

// round-nearest-even pack of two f32 into one uint (2×bf16, lo|hi<<16)
__device__ inline unsigned int bfpair(float lo, float hi) {
    unsigned int ul = __float_as_uint(lo); ul += 0x7fffu + ((ul >> 16) & 1u);
    unsigned int uh = __float_as_uint(hi); uh += 0x7fffu + ((uh >> 16) & 1u);
    return (ul >> 16) | (uh & 0xffff0000u);
}

// ---------------- MFMA GEMM + attention logits (batched over all T snapshots) ----------------
// C[nrows x 128] = A[nrows x 128] @ W[128 x 128] in bf16 MFMA (f32 accumulate).
// A-fragments loaded DIRECTLY from global (16 B/lane; bf16 rows for layer2, f32+pack for
// layer1) -- no A LDS staging, no in-loop barriers. W^T staged once in LDS (bf16, pad 136).
// Writes FP8 e4m3 C rows (hq, 128 B/row) + f32 logits vas/vad.
template <bool ABF16>
__global__ __launch_bounds__(256) void k_gemm_mfma(
    const void* __restrict__ Asrc, const float* __restrict__ W,
    const float* __restrict__ asrc, const float* __restrict__ adst,
    unsigned char* __restrict__ hq, float* __restrict__ vas, float* __restrict__ vad,
    int nrows)
{
    __shared__ unsigned short Wt[128 * 136];  // [n][k] bf16, padded
    int tid = threadIdx.x;
    int lane = tid & 63, wv = tid >> 6;
    int row0 = blockIdx.x * 128;
    int c0 = lane & 15, g = lane >> 4;

    // ---- stage Wt = W^T (once) ----
    {
        int k = tid >> 1;
        int n0 = (tid & 1) * 64;
        const float4* wr = (const float4*)&W[k * 128 + n0];
#pragma unroll
        for (int i = 0; i < 16; ++i) {
            float4 v = wr[i];
            int n = n0 + i * 4;
            Wt[(n + 0) * 136 + k] = bf16r(v.x);
            Wt[(n + 1) * 136 + k] = bf16r(v.y);
            Wt[(n + 2) * 136 + k] = bf16r(v.z);
            Wt[(n + 3) * 136 + k] = bf16r(v.w);
        }
    }
    __syncthreads();

    f32x4 acc[2][8];
#pragma unroll
    for (int mi = 0; mi < 2; ++mi)
#pragma unroll
        for (int ni = 0; ni < 8; ++ni)
#pragma unroll
            for (int q = 0; q < 4; ++q) acc[mi][ni][q] = 0.f;

    // A-fragment source rows for this lane (clamped)
    int rA[2];
#pragma unroll
    for (int mi = 0; mi < 2; ++mi)
        rA[mi] = min(row0 + wv * 32 + mi * 16 + c0, nrows - 1);

#pragma unroll
    for (int ks = 0; ks < 4; ++ks) {
        int k0 = ks * 32;
        bf16x8 af[2];
#pragma unroll
        for (int mi = 0; mi < 2; ++mi) {
            if (ABF16) {
                af[mi] = *(const bf16x8*)((const unsigned short*)Asrc + (size_t)rA[mi] * 128 + k0 + g * 8);
            } else {
                const float4* ap = (const float4*)((const float*)Asrc + (size_t)rA[mi] * 128 + k0 + g * 8);
                float4 f0 = ap[0], f1 = ap[1];
                uint4 p = make_uint4(bfpair(f0.x, f0.y), bfpair(f0.z, f0.w),
                                     bfpair(f1.x, f1.y), bfpair(f1.z, f1.w));
                af[mi] = *(bf16x8*)&p;
            }
        }
        bf16x8 bfr[8];
#pragma unroll
        for (int ni = 0; ni < 8; ++ni)
            bfr[ni] = *(const bf16x8*)&Wt[(ni * 16 + c0) * 136 + k0 + g * 8];
#pragma unroll
        for (int mi = 0; mi < 2; ++mi)
#pragma unroll
            for (int ni = 0; ni < 8; ++ni)
                acc[mi][ni] = __builtin_amdgcn_mfma_f32_16x16x32_bf16(af[mi], bfr[ni], acc[mi][ni], 0, 0, 0);
    }

    // ---- epilogue: logits (f32) + fp8 pack ----
    float as_s[8], ad_s[8];
#pragma unroll
    for (int ni = 0; ni < 8; ++ni) {
        as_s[ni] = asrc[ni * 16 + c0];
        ad_s[ni] = adst[ni * 16 + c0];
    }
#pragma unroll
    for (int mi = 0; mi < 2; ++mi) {
#pragma unroll
        for (int reg = 0; reg < 4; ++reg) {
            int row = row0 + wv * 32 + mi * 16 + g * 4 + reg;
            bool rowok = row < nrows;
            float v[8];
            float s = 0.f, d = 0.f;
#pragma unroll
            for (int ni = 0; ni < 8; ++ni) {
                v[ni] = acc[mi][ni][reg];
                s = fmaf(v[ni], as_s[ni], s);
                d = fmaf(v[ni], ad_s[ni], d);
            }
#pragma unroll
            for (int o = 1; o < 16; o <<= 1) { s += __shfl_xor(s, o); d += __shfl_xor(d, o); }
            if (rowok && c0 == 0) { vas[row] = s; vad[row] = d; }
#pragma unroll
            for (int ni = 0; ni < 8; ++ni) {
                float vn = __shfl_xor(v[ni], 1);   // all lanes execute
                unsigned int w = (unsigned int)__builtin_amdgcn_cvt_pk_fp8_f32(v[ni], vn, 0, false);
                if (rowok && (c0 & 1) == 0)
                    *(unsigned short*)&hq[(size_t)row * 128 + ni * 16 + c0] = (unsigned short)w;
            }
        }
    }
}

// ---------------- aggregation: 16-lane group per dst node, padded 16-edge chunks ----------------
// grid (gAgg, T), t-major tables. FP8 gather: 8 B/lane (8 fp8 feats), native cvt_pk unpack.
// Output bf16-packed rows (agg1 -> GEMM2 input; agg2 -> pool input).
template <bool RELU>
__global__ __launch_bounds__(256) void k_agg(const unsigned char* __restrict__ hq,
                                             const float* __restrict__ vas,
                                             const float* __restrict__ vad,
                                             const int* __restrict__ row_ptr,
                                             const int* __restrict__ csr,
                                             const float* __restrict__ bias,
                                             unsigned int* __restrict__ outb, int n) {
    int tid = threadIdx.x;
    int grp = tid >> 4, l = tid & 15;
    int w = blockIdx.x * 16 + grp;
    if (w >= n) return;
    unsigned int tbase = (unsigned int)blockIdx.y * (unsigned int)n;
    unsigned int g = tbase + (unsigned int)w;
    int beg = row_ptr[w], end = row_ptr[w + 1];
    float advl = vad[g];

    f32x2 acc2[4];
#pragma unroll
    for (int q = 0; q < 4; ++q) { acc2[q].x = 0.f; acc2[q].y = 0.f; }
    float zp = 0.f;

    for (int c = beg; c < end; c += 16) {
        int raw = csr[c + l];                       // coalesced
        unsigned int s_l = tbase + (unsigned int)(raw & 0x7fffffff);
        float e = vas[s_l] + advl;
        e = e > 0.f ? e : LEAKY * e;
        float w_l = (raw >= 0) ? __expf(e) : 0.f;   // pads contribute 0
        zp += w_l;

        unsigned int ofs[16]; float wt[16];
#pragma unroll
        for (int q = 0; q < 16; ++q) {
            ofs[q] = __shfl(s_l, q, 16) * 128u + (unsigned int)(l * 8);  // 32-bit byte offset
            wt[q] = __shfl(w_l, q, 16);
        }
        uint2 v[16];
#pragma unroll
        for (int q = 0; q < 16; ++q)
            v[q] = *(const uint2*)&hq[ofs[q]];
#pragma unroll
        for (int q = 0; q < 16; ++q) {
            f32x2 w2; w2.x = wt[q]; w2.y = wt[q];
            acc2[0] = __builtin_elementwise_fma(w2, __builtin_amdgcn_cvt_pk_f32_fp8(v[q].x, false), acc2[0]);
            acc2[1] = __builtin_elementwise_fma(w2, __builtin_amdgcn_cvt_pk_f32_fp8(v[q].x, true),  acc2[1]);
            acc2[2] = __builtin_elementwise_fma(w2, __builtin_amdgcn_cvt_pk_f32_fp8(v[q].y, false), acc2[2]);
            acc2[3] = __builtin_elementwise_fma(w2, __builtin_amdgcn_cvt_pk_f32_fp8(v[q].y, true),  acc2[3]);
        }
    }

    float z = zp;
#pragma unroll
    for (int o = 1; o < 16; o <<= 1) z += __shfl_xor(z, o, 16);
    float inv = 1.0f / z;

    float4 b0 = *(const float4*)&bias[l * 8];
    float4 b1 = *(const float4*)&bias[l * 8 + 4];
    float4 o0 = make_float4(fmaf(acc2[0].x, inv, b0.x), fmaf(acc2[0].y, inv, b0.y),
                            fmaf(acc2[1].x, inv, b0.z), fmaf(acc2[1].y, inv, b0.w));
    float4 o1 = make_float4(fmaf(acc2[2].x, inv, b1.x), fmaf(acc2[2].y, inv, b1.y),
                            fmaf(acc2[3].x, inv, b1.z), fmaf(acc2[3].y, inv, b1.w));
    if (RELU) {
        o0.x = fmaxf(o0.x, 0.f); o0.y = fmaxf(o0.y, 0.f); o0.z = fmaxf(o0.z, 0.f); o0.w = fmaxf(o0.w, 0.f);
        o1.x = fmaxf(o1.x, 0.f); o1.y = fmaxf(o1.y, 0.f); o1.z = fmaxf(o1.z, 0.f); o1.w = fmaxf(o1.w, 0.f);
    }
    uint4 p = make_uint4(bfpair(o0.x, o0.y), bfpair(o0.z, o0.w),
                         bfpair(o1.x, o1.y), bfpair(o1.z, o1.w));
    *(uint4*)&outb[(size_t)g * 64 + l * 4] = p;
}

// ---------------- batch mean pool (batch_idx sorted), bf16 t-major input ----------------
__global__ __launch_bounds__(128) void k_pool(const unsigned int* __restrict__ h,
                                              const int* __restrict__ bstart,
                                              float* __restrict__ out, int n, int T) {
    int b = blockIdx.x;
    int chunk = blockIdx.y;
    int t = blockIdx.z;
    int f = threadIdx.x;
    int s = bstart[b], e = bstart[b + 1];
    int cnt = e - s;
    if (cnt <= 0) return;
    int len = (cnt + 31) / 32;
    int cs = s + chunk * len;
    int ce = min(cs + len, e);
    if (cs >= ce) return;
    const unsigned int* ht = h + (size_t)t * n * 64;
    float acc = 0.f;
    for (int nidx = cs; nidx < ce; ++nidx) {
        unsigned int v = ht[(size_t)nidx * 64 + (f >> 1)];
        acc += __uint_as_float((f & 1) ? (v & 0xffff0000u) : (v << 16));
    }
    atomicAdd(&out[(size_t)(b * T + t) * 128 + f], acc / (float)cnt);
}

// ---------------- launch ----------------

extern "C" void kernel_launch(void* const* d_in, const int* in_sizes, int n_in,
                              void* d_out, int out_size, void* d_ws, size_t ws_size,
                              hipStream_t stream) {
    const float* x    = (const float*)d_in[0];
    const int*   ei   = (const int*)d_in[1];
    const int*   bidx = (const int*)d_in[2];
    const float* W1   = (const float*)d_in[3];
    const float* as1  = (const float*)d_in[4];
    const float* ad1  = (const float*)d_in[5];
    const float* b1   = (const float*)d_in[6];
    const float* W2   = (const float*)d_in[7];
    const float* as2  = (const float*)d_in[8];
    const float* ad2  = (const float*)d_in[9];
    const float* b2   = (const float*)d_in[10];
    float* out = (float*)d_out;

    const int E = in_sizes[1] / 2;
    const int N = in_sizes[2];
    const int T = in_sizes[0] / (N * 128);
    const int B = out_size / (T * 128);
    const int* src = ei;
    const int* dst = ei + E;
    const int NT = N * T;

    char* wsp = (char*)d_ws;
    auto alloc = [&](size_t bytes) { void* p = wsp; wsp += (bytes + 255) / 256 * 256; return p; };
    unsigned char* hq    = (unsigned char*)alloc((size_t)NT * 128);    // fp8 GEMM out (gather table)
    unsigned int* hb2    = (unsigned int*)alloc((size_t)NT * 64 * 4);  // bf16 agg out, t-major
    float* vas           = (float*)alloc((size_t)NT * 4);
    float* vad           = (float*)alloc((size_t)NT * 4);
    int* row_ptr         = (int*)alloc((size_t)(N + 1) * 4);
    int* cnt             = (int*)alloc((size_t)N * 4);                 // reused as scatter cursor
    int* csr             = (int*)alloc(((size_t)E + 16ull * N + 64) * 4); // padded CSR
    int* bstart          = (int*)alloc((size_t)(B + 2) * 4);
    int  nScanB          = (N + 255) / 256;
    int* bsum            = (int*)alloc((size_t)nScanB * 4);
    int* boff            = (int*)alloc((size_t)nScanB * 4);

    hipMemsetAsync(d_out, 0, (size_t)out_size * sizeof(float), stream);

    int gN = (N + 255) / 256, gE = (E + 255) / 256;
    k_init<<<gN, 256, 0, stream>>>(cnt, bstart, N, B + 1);
    k_count<<<gE, 256, 0, stream>>>(dst, cnt, E);
    k_scanA<<<nScanB, 256, 0, stream>>>(cnt, bsum, N);
    k_scanB<<<1, 256, 0, stream>>>(bsum, boff, nScanB);
    k_scanC<<<nScanB, 256, 0, stream>>>(cnt, boff, row_ptr, N);
    k_selfloop<<<gN, 256, 0, stream>>>(row_ptr, csr, cnt, N);
    k_scatter<<<gE, 256, 0, stream>>>(src, dst, cnt, csr, E);
    k_pad<<<gN, 256, 0, stream>>>(row_ptr, cnt, csr, N);
    k_bbounds<<<gN, 256, 0, stream>>>(bidx, bstart, N);
    k_bfix<<<1, 1, 0, stream>>>(bstart, N, B);

    int gGemm = (NT + 127) / 128;
    int gAgg = (N + 15) / 16;  // 16 nodes (16-lane groups) per 256-thread block
    k_gemm_mfma<false><<<gGemm, 256, 0, stream>>>(x,   W1, as1, ad1, hq, vas, vad, NT);
    k_agg<true ><<<dim3(gAgg, T), 256, 0, stream>>>(hq, vas, vad, row_ptr, csr, b1, hb2, N);
    k_gemm_mfma<true ><<<gGemm, 256, 0, stream>>>(hb2, W2, as2, ad2, hq, vas, vad, NT);
    k_agg<false><<<dim3(gAgg, T), 256, 0, stream>>>(hq, vas, vad, row_ptr, csr, b2, hb2, N);
    k_pool<<<dim3(B, 32, T), 128, 0, stream>>>(hb2, bstart, out, N, T);
}